// Round 1
// baseline (275.328 us; speedup 1.0000x reference)
//
#include <hip/hip_runtime.h>

#define N_SEQ 1024
#define B_SZ 8
#define C_DIM 256
#define K_HEADS 4
#define FF_DIM 2048

typedef short s16x8 __attribute__((ext_vector_type(8)));
typedef float f32x4v __attribute__((ext_vector_type(4)));

__device__ __forceinline__ unsigned short f2bf(float f) {
    unsigned u = __builtin_bit_cast(unsigned, f);
    u += 0x7FFFu + ((u >> 16) & 1u);
    return (unsigned short)(u >> 16);
}

// ---------------- prep kernels ----------------

__global__ __launch_bounds__(256) void prep_q_kernel(const float* __restrict__ src,
                                                     const float* __restrict__ pos,
                                                     unsigned short* __restrict__ qb) {
    int t = blockIdx.x * 256 + threadIdx.x;      // 524288 threads, 4 elems each
    int i4 = t * 4;
    int n = i4 >> 11;            // / (B*C = 2048)
    int rem = i4 & 2047;
    int b = rem >> 8;
    int c = rem & 255;
    float4 s = *reinterpret_cast<const float4*>(src + i4);
    float4 p = *reinterpret_cast<const float4*>(pos + i4);
    int out = (b * N_SEQ + n) * C_DIM + c;
    *reinterpret_cast<ushort4*>(qb + out) = make_ushort4(
        f2bf((s.x + p.x) * 0.0625f), f2bf((s.y + p.y) * 0.0625f),
        f2bf((s.z + p.z) * 0.0625f), f2bf((s.w + p.w) * 0.0625f));
}

__global__ __launch_bounds__(256) void prep_kv_kernel(const float* __restrict__ matched,
                                                      const float* __restrict__ pos,
                                                      unsigned short* __restrict__ kb,
                                                      unsigned short* __restrict__ vb) {
    int t = blockIdx.x * 256 + threadIdx.x;      // 2097152 threads, 4 elems each
    long long i4 = (long long)t * 4;
    int k = (int)(i4 >> 21);                     // / (N*B*C = 2^21)
    int rem = (int)(i4 & ((1 << 21) - 1));
    int n = rem >> 11;
    int rem2 = rem & 2047;
    int b = rem2 >> 8;
    int c = rem2 & 255;
    float4 m = *reinterpret_cast<const float4*>(matched + i4);
    float4 p = *reinterpret_cast<const float4*>(pos + rem);
    size_t out = ((size_t)((k * B_SZ + b) * N_SEQ + n)) * C_DIM + c;
    *reinterpret_cast<ushort4*>(kb + out) = make_ushort4(
        f2bf(m.x + p.x), f2bf(m.y + p.y), f2bf(m.z + p.z), f2bf(m.w + p.w));
    *reinterpret_cast<ushort4*>(vb + out) = make_ushort4(
        f2bf(m.x), f2bf(m.y), f2bf(m.z), f2bf(m.w));
}

// Wt[c*R + r] = bf16(W[r*Cn + c])   (W is R x Cn, Wt is Cn x R)
__global__ __launch_bounds__(256) void transpose_w_kernel(const float* __restrict__ W,
                                                          unsigned short* __restrict__ Wt,
                                                          int R, int Cn) {
    int idx = blockIdx.x * 256 + threadIdx.x;
    int c = idx / R;
    int r = idx - c * R;
    Wt[idx] = f2bf(W[(size_t)r * Cn + c]);
}

// ---------------- flash attention ----------------
// grid = (K*B) * (N/64) blocks, 256 threads (4 waves, each 16 q-rows)
__global__ __launch_bounds__(256) void attn_kernel(const unsigned short* __restrict__ qb,
                                                   const unsigned short* __restrict__ kb,
                                                   const unsigned short* __restrict__ vb,
                                                   const float* __restrict__ mask,
                                                   unsigned short* __restrict__ att) {
    __shared__ unsigned short Kl[32][264];
    __shared__ unsigned short Vl[32][264];
    __shared__ unsigned short Pl[4][16][40];

    int blk = blockIdx.x;
    int qt   = blk & 15;          // N/64 = 16 q-tiles
    int pr   = blk >> 4;          // pair index k*B + b
    int kidx = pr >> 3;
    int b    = pr & 7;
    int tid = threadIdx.x, wid = tid >> 6, lane = tid & 63;
    int l15 = lane & 15, lg = lane >> 4;

    int q0 = qt * 64 + wid * 16;

    // Q fragments, 16x256 per wave (A-layout: row=l15, k=lg*8+i within 32-chunk)
    s16x8 qf[8];
    const unsigned short* qrow = qb + ((size_t)(b * N_SEQ + q0 + l15)) * C_DIM + lg * 8;
#pragma unroll
    for (int cc = 0; cc < 8; cc++)
        qf[cc] = *reinterpret_cast<const s16x8*>(qrow + cc * 32);

    f32x4v oacc[16];
#pragma unroll
    for (int i = 0; i < 16; i++) oacc[i] = (f32x4v){0.f, 0.f, 0.f, 0.f};
    float mrun[4] = {-INFINITY, -INFINITY, -INFINITY, -INFINITY};
    float lrun[4] = {0.f, 0.f, 0.f, 0.f};

    size_t kvbase = ((size_t)(kidx * B_SZ + b)) * N_SEQ * C_DIM;
    const float* mbase = mask + ((size_t)b * N_SEQ) * N_SEQ;

    for (int kv0 = 0; kv0 < N_SEQ; kv0 += 32) {
        __syncthreads();   // previous-iter LDS reads complete
        // stage K,V tiles (32 rows x 256 c)
#pragma unroll
        for (int i = 0; i < 4; i++) {
            int ch = tid + i * 256;
            int r = ch >> 5, c8 = (ch & 31) * 8;
            size_t ga = kvbase + (size_t)(kv0 + r) * C_DIM + c8;
            *reinterpret_cast<s16x8*>(&Kl[r][c8]) = *reinterpret_cast<const s16x8*>(kb + ga);
            *reinterpret_cast<s16x8*>(&Vl[r][c8]) = *reinterpret_cast<const s16x8*>(vb + ga);
        }
        __syncthreads();

        // S = Q K^T  (two 16x16 col-tiles)
        f32x4v s0 = {0.f, 0.f, 0.f, 0.f}, s1 = {0.f, 0.f, 0.f, 0.f};
#pragma unroll
        for (int cc = 0; cc < 8; cc++) {
            s16x8 k0 = *reinterpret_cast<const s16x8*>(&Kl[l15][cc * 32 + lg * 8]);
            s16x8 k1 = *reinterpret_cast<const s16x8*>(&Kl[16 + l15][cc * 32 + lg * 8]);
            s0 = __builtin_amdgcn_mfma_f32_16x16x32_bf16(qf[cc], k0, s0, 0, 0, 0);
            s1 = __builtin_amdgcn_mfma_f32_16x16x32_bf16(qf[cc], k1, s1, 0, 0, 0);
        }
        // additive mask
#pragma unroll
        for (int j = 0; j < 4; j++) {
            const float* mr = mbase + (size_t)(q0 + lg * 4 + j) * N_SEQ + kv0;
            s0[j] += mr[l15];
            s1[j] += mr[16 + l15];
        }
        // online softmax (rows live in 16-lane groups)
        float pm[4], sc[4];
#pragma unroll
        for (int j = 0; j < 4; j++) pm[j] = fmaxf(s0[j], s1[j]);
#pragma unroll
        for (int d = 1; d < 16; d <<= 1) {
#pragma unroll
            for (int j = 0; j < 4; j++) pm[j] = fmaxf(pm[j], __shfl_xor(pm[j], d));
        }
#pragma unroll
        for (int j = 0; j < 4; j++) {
            float mn = fmaxf(mrun[j], pm[j]);
            sc[j] = __expf(mrun[j] - mn);
            mrun[j] = mn;
        }
        float p0[4], p1[4], ps[4];
#pragma unroll
        for (int j = 0; j < 4; j++) {
            p0[j] = __expf(s0[j] - mrun[j]);
            p1[j] = __expf(s1[j] - mrun[j]);
            ps[j] = p0[j] + p1[j];
        }
#pragma unroll
        for (int d = 1; d < 16; d <<= 1) {
#pragma unroll
            for (int j = 0; j < 4; j++) ps[j] += __shfl_xor(ps[j], d);
        }
#pragma unroll
        for (int j = 0; j < 4; j++) lrun[j] = lrun[j] * sc[j] + ps[j];
#pragma unroll
        for (int ct = 0; ct < 16; ct++) {
#pragma unroll
            for (int j = 0; j < 4; j++) oacc[ct][j] *= sc[j];
        }
        // P (C/D layout) -> LDS -> A-fragment layout
#pragma unroll
        for (int j = 0; j < 4; j++) {
            Pl[wid][lg * 4 + j][l15]      = f2bf(p0[j]);
            Pl[wid][lg * 4 + j][16 + l15] = f2bf(p1[j]);
        }
        __syncthreads();
        s16x8 pf = *reinterpret_cast<const s16x8*>(&Pl[wid][l15][lg * 8]);
        // O += P V
#pragma unroll
        for (int ct = 0; ct < 16; ct++) {
            s16x8 vf;
#pragma unroll
            for (int i = 0; i < 8; i++) vf[i] = (short)Vl[lg * 8 + i][ct * 16 + l15];
            oacc[ct] = __builtin_amdgcn_mfma_f32_16x16x32_bf16(pf, vf, oacc[ct], 0, 0, 0);
        }
    }

    float inv[4];
#pragma unroll
    for (int j = 0; j < 4; j++) inv[j] = 1.0f / lrun[j];
#pragma unroll
    for (int ct = 0; ct < 16; ct++) {
#pragma unroll
        for (int j = 0; j < 4; j++) {
            size_t oi = ((size_t)(b * N_SEQ + q0 + lg * 4 + j)) * (K_HEADS * C_DIM)
                        + kidx * C_DIM + ct * 16 + l15;
            att[oi] = f2bf(oacc[ct][j] * inv[j]);
        }
    }
}

// ---------------- GEMM: C = A(MxK) * Bt(NxK)^T + bias ----------------
template <int RELU, int OUTBF>
__global__ __launch_bounds__(256) void gemm_bt_kernel(const unsigned short* __restrict__ A,
                                                      const unsigned short* __restrict__ Bt,
                                                      const float* __restrict__ bias,
                                                      float* __restrict__ Cf,
                                                      unsigned short* __restrict__ Cb,
                                                      int M, int Nn, int Kd) {
    __shared__ unsigned short Al[128][40];
    __shared__ unsigned short Bl[128][40];
    int tm0 = blockIdx.y * 128;
    int tn0 = blockIdx.x * 128;
    int tid = threadIdx.x, wid = tid >> 6, lane = tid & 63;
    int l15 = lane & 15, lg = lane >> 4;
    int wm = (wid >> 1) * 64, wn = (wid & 1) * 64;

    f32x4v acc[4][4];
#pragma unroll
    for (int i = 0; i < 4; i++)
#pragma unroll
        for (int j = 0; j < 4; j++) acc[i][j] = (f32x4v){0.f, 0.f, 0.f, 0.f};

    for (int k0 = 0; k0 < Kd; k0 += 32) {
        __syncthreads();
#pragma unroll
        for (int i = 0; i < 2; i++) {
            int ch = tid + i * 256;
            int r = ch >> 2, c8 = (ch & 3) * 8;
            *reinterpret_cast<s16x8*>(&Al[r][c8]) =
                *reinterpret_cast<const s16x8*>(A + (size_t)(tm0 + r) * Kd + k0 + c8);
            *reinterpret_cast<s16x8*>(&Bl[r][c8]) =
                *reinterpret_cast<const s16x8*>(Bt + (size_t)(tn0 + r) * Kd + k0 + c8);
        }
        __syncthreads();
        s16x8 af[4], bf[4];
#pragma unroll
        for (int t = 0; t < 4; t++) {
            af[t] = *reinterpret_cast<const s16x8*>(&Al[wm + t * 16 + l15][lg * 8]);
            bf[t] = *reinterpret_cast<const s16x8*>(&Bl[wn + t * 16 + l15][lg * 8]);
        }
#pragma unroll
        for (int mt = 0; mt < 4; mt++)
#pragma unroll
            for (int nt = 0; nt < 4; nt++)
                acc[mt][nt] = __builtin_amdgcn_mfma_f32_16x16x32_bf16(af[mt], bf[nt], acc[mt][nt], 0, 0, 0);
    }

#pragma unroll
    for (int mt = 0; mt < 4; mt++) {
#pragma unroll
        for (int nt = 0; nt < 4; nt++) {
#pragma unroll
            for (int j = 0; j < 4; j++) {
                int row = tm0 + wm + mt * 16 + lg * 4 + j;
                int col = tn0 + wn + nt * 16 + l15;
                float v = acc[mt][nt][j] + bias[col];
                if (RELU) v = fmaxf(v, 0.f);
                if (OUTBF) Cb[(size_t)row * Nn + col] = f2bf(v);
                else       Cf[(size_t)row * Nn + col] = v;
            }
        }
    }
}

// ---------------- fused residual + LayerNorm ----------------
// rows r = n*B + b ; x = src[r] + recT[(b,n)] ; outputs f32 + bf16
__global__ __launch_bounds__(256) void ln1_kernel(const float* __restrict__ src,
                                                  const float* __restrict__ recT,
                                                  const float* __restrict__ g,
                                                  const float* __restrict__ be,
                                                  float* __restrict__ outf,
                                                  unsigned short* __restrict__ outb) {
    int r = blockIdx.x * 4 + (threadIdx.x >> 6);
    int lane = threadIdx.x & 63;
    int n = r >> 3, b = r & 7;
    int c = lane * 4;
    float4 xs = *reinterpret_cast<const float4*>(src + (size_t)r * C_DIM + c);
    float4 xr = *reinterpret_cast<const float4*>(recT + ((size_t)(b * N_SEQ + n)) * C_DIM + c);
    float x[4] = {xs.x + xr.x, xs.y + xr.y, xs.z + xr.z, xs.w + xr.w};
    float s = x[0] + x[1] + x[2] + x[3];
    float q = x[0] * x[0] + x[1] * x[1] + x[2] * x[2] + x[3] * x[3];
#pragma unroll
    for (int d = 1; d < 64; d <<= 1) {
        s += __shfl_xor(s, d);
        q += __shfl_xor(q, d);
    }
    float mean = s * (1.f / 256.f);
    float var = q * (1.f / 256.f) - mean * mean;
    float rstd = rsqrtf(var + 1e-5f);
    float4 gv = *reinterpret_cast<const float4*>(g + c);
    float4 bv = *reinterpret_cast<const float4*>(be + c);
    float y0 = (x[0] - mean) * rstd * gv.x + bv.x;
    float y1 = (x[1] - mean) * rstd * gv.y + bv.y;
    float y2 = (x[2] - mean) * rstd * gv.z + bv.z;
    float y3 = (x[3] - mean) * rstd * gv.w + bv.w;
    *reinterpret_cast<float4*>(outf + (size_t)r * C_DIM + c) = make_float4(y0, y1, y2, y3);
    *reinterpret_cast<ushort4*>(outb + (size_t)r * C_DIM + c) =
        make_ushort4(f2bf(y0), f2bf(y1), f2bf(y2), f2bf(y3));
}

__global__ __launch_bounds__(256) void ln2_kernel(const float* __restrict__ rec1f,
                                                  const float* __restrict__ ffn,
                                                  const float* __restrict__ g,
                                                  const float* __restrict__ be,
                                                  float* __restrict__ out) {
    int r = blockIdx.x * 4 + (threadIdx.x >> 6);
    int lane = threadIdx.x & 63;
    int c = lane * 4;
    size_t base = (size_t)r * C_DIM + c;
    float4 xa = *reinterpret_cast<const float4*>(rec1f + base);
    float4 xb = *reinterpret_cast<const float4*>(ffn + base);
    float x[4] = {xa.x + xb.x, xa.y + xb.y, xa.z + xb.z, xa.w + xb.w};
    float s = x[0] + x[1] + x[2] + x[3];
    float q = x[0] * x[0] + x[1] * x[1] + x[2] * x[2] + x[3] * x[3];
#pragma unroll
    for (int d = 1; d < 64; d <<= 1) {
        s += __shfl_xor(s, d);
        q += __shfl_xor(q, d);
    }
    float mean = s * (1.f / 256.f);
    float var = q * (1.f / 256.f) - mean * mean;
    float rstd = rsqrtf(var + 1e-5f);
    float4 gv = *reinterpret_cast<const float4*>(g + c);
    float4 bv = *reinterpret_cast<const float4*>(be + c);
    *reinterpret_cast<float4*>(out + base) = make_float4(
        (x[0] - mean) * rstd * gv.x + bv.x,
        (x[1] - mean) * rstd * gv.y + bv.y,
        (x[2] - mean) * rstd * gv.z + bv.z,
        (x[3] - mean) * rstd * gv.w + bv.w);
}

// ---------------- launch ----------------

extern "C" void kernel_launch(void* const* d_in, const int* in_sizes, int n_in,
                              void* d_out, int out_size, void* d_ws, size_t ws_size,
                              hipStream_t stream) {
    const float* src   = (const float*)d_in[0];
    const float* match = (const float*)d_in[1];
    const float* pos   = (const float*)d_in[2];
    const float* mask  = (const float*)d_in[3];
    const float* Wagg  = (const float*)d_in[4];
    const float* bagg  = (const float*)d_in[5];
    const float* W1    = (const float*)d_in[6];
    const float* b1    = (const float*)d_in[7];
    const float* W2    = (const float*)d_in[8];
    const float* b2    = (const float*)d_in[9];
    const float* g1    = (const float*)d_in[10];
    const float* be1   = (const float*)d_in[11];
    const float* g2    = (const float*)d_in[12];
    const float* be2   = (const float*)d_in[13];

    char* ws = (char*)d_ws;
    unsigned short* qb    = (unsigned short*)(ws + 0);          //  4 MB  (B,N,C) bf16, pre-scaled
    unsigned short* kb    = (unsigned short*)(ws + 4194304);    // 16 MB  (K,B,N,C) bf16
    unsigned short* vb    = (unsigned short*)(ws + 20971520);   // 16 MB
    unsigned short* att   = (unsigned short*)(ws + 37748736);   // 16 MB  (B,N,K*C) bf16
    unsigned short* WaggT = (unsigned short*)(ws + 54525952);   // 0.5 MB (C x K*C)
    unsigned short* W1T   = (unsigned short*)(ws + 55050240);   // 1 MB   (FF x C)
    unsigned short* W2T   = (unsigned short*)(ws + 56098816);   // 1 MB   (C x FF)
    float*          rec_t = (float*)(ws + 57147392);            // 8 MB   (B,N,C) f32
    float*          rec1f = (float*)(ws + 65536000);            // 8 MB   (N,B,C) f32
    unsigned short* rec1b = (unsigned short*)(ws + 73924608);   // 4 MB   bf16
    unsigned short* hid   = (unsigned short*)(ws + 4194304);    // 32 MB, aliases kb+vb (dead)
    float*          ffn   = (float*)(ws + 57147392);            // 8 MB, aliases rec_t (dead)
    float* outp = (float*)d_out;

    prep_q_kernel<<<2048, 256, 0, stream>>>(src, pos, qb);
    prep_kv_kernel<<<8192, 256, 0, stream>>>(match, pos, kb, vb);
    transpose_w_kernel<<<1024, 256, 0, stream>>>(Wagg, WaggT, K_HEADS * C_DIM, C_DIM);
    transpose_w_kernel<<<2048, 256, 0, stream>>>(W1, W1T, C_DIM, FF_DIM);
    transpose_w_kernel<<<2048, 256, 0, stream>>>(W2, W2T, FF_DIM, C_DIM);

    attn_kernel<<<K_HEADS * B_SZ * (N_SEQ / 64), 256, 0, stream>>>(qb, kb, vb, mask, att);

    // rec_t(B,N,C) = att(B*N, K*C) @ Wagg + bagg
    gemm_bt_kernel<0, 0><<<dim3(2, 64), 256, 0, stream>>>(att, WaggT, bagg, rec_t, nullptr,
                                                          B_SZ * N_SEQ, C_DIM, K_HEADS * C_DIM);
    ln1_kernel<<<2048, 256, 0, stream>>>(src, rec_t, g1, be1, rec1f, rec1b);
    // hid = relu(rec1 @ W1 + b1)
    gemm_bt_kernel<1, 1><<<dim3(16, 64), 256, 0, stream>>>(rec1b, W1T, b1, nullptr, hid,
                                                           N_SEQ * B_SZ, FF_DIM, C_DIM);
    // ffn = hid @ W2 + b2
    gemm_bt_kernel<0, 0><<<dim3(2, 64), 256, 0, stream>>>(hid, W2T, b2, ffn, nullptr,
                                                          N_SEQ * B_SZ, C_DIM, FF_DIM);
    ln2_kernel<<<2048, 256, 0, stream>>>(rec1f, ffn, g2, be2, outp);
}